// Round 3
// baseline (1760.495 us; speedup 1.0000x reference)
//
#include <hip/hip_runtime.h>

#define N_NODES 100000
#define N_EDGES 1200000
#define DIM     64
#define N_LAYERS 3
#define N_GRAPHS 512
#define OUTD    192   // 3 * 64, concat layout
#define BN_EPS  1e-5f

#define NPB 64            // nodes per block in layer_kernel
#define LDS_PITCH 65      // +1 pad -> 2-way bank aliasing only (free)
#define NLBLK ((N_NODES + NPB - 1) / NPB)                 // 1563

// ---- two-level binning geometry ----
#define BSHIFT 9
#define BUCK_NODES (1 << BSHIFT)                          // 512 nodes / bucket
#define NBUK ((N_NODES + BUCK_NODES - 1) / BUCK_NODES)    // 196
#define EPB 4096                                          // edges per partition block
#define NPBLK ((N_EDGES + EPB - 1) / EPB)                 // 293

// ---------------------------------------------------------------------------
// Transpose W1/W2 (per layer): WT[l][k][j] = W[l][j][k]. Also writes the
// identity affine block (scale=1, shift=0) used by layer 0.
__global__ void transpose_w(const float* __restrict__ W1, const float* __restrict__ W2,
                            float* __restrict__ W1T, float* __restrict__ W2T,
                            float* __restrict__ idaff) {
    int idx = blockIdx.x * blockDim.x + threadIdx.x;  // L*64*64
    if (idx < 128) idaff[idx] = (idx < 64) ? 1.0f : 0.0f;
    if (idx >= N_LAYERS * DIM * DIM) return;
    int l = idx >> 12;
    int r = idx & 4095;
    int j = r >> 6;
    int k = r & 63;
    int dstp = (l << 12) + k * DIM + j;
    W1T[dstp] = W1[idx];
    W2T[dstp] = W2[idx];
}

// ---------------------------------------------------------------------------
// Phase A: per-block bucket histogram (LDS atomics) + global bucket totals
// (196 addresses x 293 adds each, spread over time -> negligible contention).
__global__ void __launch_bounds__(256) part_hist(const int* __restrict__ dst,
                                                 int* __restrict__ hist,
                                                 int* __restrict__ tot) {
    __shared__ int h[NBUK];
    int t = threadIdx.x;
    if (t < NBUK) h[t] = 0;
    __syncthreads();
    int base = blockIdx.x * EPB;
    for (int i = t; i < EPB; i += 256) {
        int e = base + i;
        if (e < N_EDGES) atomicAdd(&h[dst[e] >> BSHIFT], 1);
    }
    __syncthreads();
    if (t < NBUK) {
        int v = h[t];
        hist[blockIdx.x * NBUK + t] = v;
        if (v) atomicAdd(&tot[t], v);
    }
}

// ---------------------------------------------------------------------------
// Phase B1: scan 196 bucket totals -> bucket starts. One tiny block.
__global__ void __launch_bounds__(256) scan196(const int* __restrict__ tot,
                                               int* __restrict__ bstart) {
    __shared__ int lds[256];
    int t = threadIdx.x;
    int v = (t < NBUK) ? tot[t] : 0;
    lds[t] = v;
    __syncthreads();
    for (int o = 1; o < 256; o <<= 1) {
        int add = (t >= o) ? lds[t - o] : 0;
        __syncthreads();
        lds[t] += add;
        __syncthreads();
    }
    if (t < NBUK) bstart[t] = lds[t] - v;   // exclusive
    if (t == 0) bstart[NBUK] = N_EDGES;
}

// ---------------------------------------------------------------------------
// Phase B2: per-(block,bucket) bases. Block b scans hist column b (293
// entries) in LDS -- parallel loads, parallel scan.
__global__ void __launch_bounds__(256) base_fill(const int* __restrict__ hist,
                                                 const int* __restrict__ bstart,
                                                 int* __restrict__ base) {
    __shared__ int c[512];
    __shared__ int ssum[256];
    int b = blockIdx.x, t = threadIdx.x;
    c[t] = (t < NPBLK) ? hist[t * NBUK + b] : 0;
    c[t + 256] = (t + 256 < NPBLK) ? hist[(t + 256) * NBUK + b] : 0;
    __syncthreads();
    int c0 = c[2 * t], c1 = c[2 * t + 1];
    int ps = c0 + c1;
    ssum[t] = ps;
    __syncthreads();
    int v = ps;
    for (int o = 1; o < 256; o <<= 1) {
        int add = (t >= o) ? ssum[t - o] : 0;
        __syncthreads();
        ssum[t] += add;
        __syncthreads();
    }
    int excl = ssum[t] - v + bstart[b];     // exclusive over pairs + bucket base
    if (2 * t < NPBLK)     base[(2 * t) * NBUK + b] = excl;
    if (2 * t + 1 < NPBLK) base[(2 * t + 1) * NBUK + b] = excl + c0;
}

// ---------------------------------------------------------------------------
// Phase C: scatter edges into bucket-partitioned order. Each (block,bucket)
// range is disjoint (deterministic bases), LDS cursors only. Packs
// (src | dstLocal<<17, w) into one int2 (src<2^17, dstLocal<2^9).
__global__ void __launch_bounds__(256) part_scatter(
        const int* __restrict__ src, const int* __restrict__ dst,
        const float* __restrict__ ew, const int* __restrict__ base,
        int2* __restrict__ pp) {
    __shared__ int cur[NBUK];
    int t = threadIdx.x;
    if (t < NBUK) cur[t] = base[blockIdx.x * NBUK + t];
    __syncthreads();
    int bb = blockIdx.x * EPB;
    for (int i = t; i < EPB; i += 256) {
        int e = bb + i;
        if (e < N_EDGES) {
            int d = dst[e];
            int bk = d >> BSHIFT;
            int pos = atomicAdd(&cur[bk], 1);
            int dl = d & (BUCK_NODES - 1);
            pp[pos] = make_int2(src[e] | (dl << 17), __float_as_int(ew[e]));
        }
    }
}

// ---------------------------------------------------------------------------
// Phase D: per-bucket counting sort -> CSR. All scattered writes confined to
// the bucket's ~48KB edge window (L2-resident, dense writebacks).
// pe.x = src | (dst&63)<<17 : the 6-bit node index within the 64-aligned
// layer-block (valid since BUCK_NODES and NPB are both 64-aligned).
__global__ void __launch_bounds__(256) csr_build(
        const int2* __restrict__ pp, const int* __restrict__ bstart,
        int* __restrict__ seg, int2* __restrict__ pe) {
    __shared__ int cnt[BUCK_NODES];
    __shared__ int ssum[256];
    int b = blockIdx.x, t = threadIdx.x;
    int ebeg = bstart[b], eend = bstart[b + 1];
    cnt[t] = 0;
    cnt[t + 256] = 0;
    __syncthreads();
    for (int e = ebeg + t; e < eend; e += 256)
        atomicAdd(&cnt[pp[e].x >> 17], 1);
    __syncthreads();
    // scan over 512 counts: thread t owns pair (2t, 2t+1)
    int c0 = cnt[2 * t], c1 = cnt[2 * t + 1];
    int ps = c0 + c1;
    ssum[t] = ps;
    __syncthreads();
    int v = ps;
    for (int o = 1; o < 256; o <<= 1) {
        int add = (t >= o) ? ssum[t - o] : 0;
        __syncthreads();
        ssum[t] += add;
        __syncthreads();
    }
    int excl = ssum[t] - v;           // exclusive over pairs
    int o0 = ebeg + excl;
    int o1 = o0 + c0;
    int n0 = (b << BSHIFT) + 2 * t;
    if (n0 < N_NODES) seg[n0] = o0;
    if (n0 + 1 < N_NODES) seg[n0 + 1] = o1;
    __syncthreads();                  // all cnt reads (c0,c1) retired
    cnt[2 * t] = o0;                  // reuse as cursors (global positions)
    cnt[2 * t + 1] = o1;
    __syncthreads();
    for (int e = ebeg + t; e < eend; e += 256) {
        int2 p = pp[e];
        int pos = atomicAdd(&cnt[p.x >> 17], 1);
        int dl6 = (p.x >> 17) & 63;   // node index within 64-node layer block
        pe[pos] = make_int2((p.x & 0x1FFFF) | (dl6 << 17), p.y);
    }
    if (b == 0 && t == 0) seg[N_NODES] = N_EDGES;
}

// ---------------------------------------------------------------------------
// Fused layer (CSR, EDGE-PARALLEL gather): R2 showed per-node accumulator
// chains cap gather ILP (~4 loads then stall; deg 12 means unroll-8 never
// engages) and per-node seg s_loads serialize. Now: each wave strides the
// block's contiguous edge range (stride 4, unroll 8) -> 8 fully independent
// x-row loads in flight, retired into LDS agg[dl][lane] via ds_add_f32.
// Per-node weight-sums via lane-0 LDS atomic. Fixup pass folds self-term +
// input BN affine. GEMM phases unchanged. LDS back to 16.9KB (occupancy).
__global__ void __launch_bounds__(256) layer_kernel(
    const float* __restrict__ x_in, int xstride,
    const int* __restrict__ seg,     // CSR offsets (N+1)
    const int2* __restrict__ pe,     // src | (dst&63)<<17, weight
    const float* __restrict__ affine /* [128]: scale|shift of input */,
    const float* __restrict__ W1T, const float* __restrict__ b1,
    const float* __restrict__ W2T, const float* __restrict__ b2,
    float* __restrict__ out /* xs base + layer*64, row stride OUTD */,
    float* __restrict__ pstat /* [NLBLK][128]: sum|sumsq partials */) {
    __shared__ float lds[NPB * LDS_PITCH];
    __shared__ float wsum[NPB];
    int t = threadIdx.x;
    int lane = t & 63;
    int wid = __builtin_amdgcn_readfirstlane(t >> 6);   // wave id 0..3, SGPR
    int nbase = blockIdx.x * NPB;
    int nend = (nbase + NPB < N_NODES) ? nbase + NPB : N_NODES;

    // zero accumulators
    for (int i = t; i < NPB * LDS_PITCH; i += 256) lds[i] = 0.0f;
    if (t < NPB) wsum[t] = 0.0f;

    float sc_in = affine[lane];          // coalesced 256B, once
    float sh_in = affine[64 + lane];
    int eb = seg[nbase];
    int ee = seg[nend];
    __syncthreads();

    // ---- Phase 1: edge-parallel gather ----
    int e = eb + wid;                    // wave-uniform -> pe[e] is s_load
#define EDGE_DECODE(p, w, s, d)                                                \
    float w = __int_as_float(p.y);                                             \
    int s = p.x & 0x1FFFF;                                                     \
    int d = p.x >> 17;
    for (; e + 28 < ee; e += 32) {       // 8 edges of this wave per iter
        int2 p0 = pe[e];      int2 p1 = pe[e + 4];
        int2 p2 = pe[e + 8];  int2 p3 = pe[e + 12];
        int2 p4 = pe[e + 16]; int2 p5 = pe[e + 20];
        int2 p6 = pe[e + 24]; int2 p7 = pe[e + 28];
        EDGE_DECODE(p0, w0, s0, d0) EDGE_DECODE(p1, w1, s1, d1)
        EDGE_DECODE(p2, w2, s2, d2) EDGE_DECODE(p3, w3, s3, d3)
        EDGE_DECODE(p4, w4, s4, d4) EDGE_DECODE(p5, w5, s5, d5)
        EDGE_DECODE(p6, w6, s6, d6) EDGE_DECODE(p7, w7, s7, d7)
        float v0 = w0 * x_in[(size_t)s0 * xstride + lane];
        float v1 = w1 * x_in[(size_t)s1 * xstride + lane];
        float v2 = w2 * x_in[(size_t)s2 * xstride + lane];
        float v3 = w3 * x_in[(size_t)s3 * xstride + lane];
        float v4 = w4 * x_in[(size_t)s4 * xstride + lane];
        float v5 = w5 * x_in[(size_t)s5 * xstride + lane];
        float v6 = w6 * x_in[(size_t)s6 * xstride + lane];
        float v7 = w7 * x_in[(size_t)s7 * xstride + lane];
        atomicAdd(&lds[d0 * LDS_PITCH + lane], v0);
        atomicAdd(&lds[d1 * LDS_PITCH + lane], v1);
        atomicAdd(&lds[d2 * LDS_PITCH + lane], v2);
        atomicAdd(&lds[d3 * LDS_PITCH + lane], v3);
        atomicAdd(&lds[d4 * LDS_PITCH + lane], v4);
        atomicAdd(&lds[d5 * LDS_PITCH + lane], v5);
        atomicAdd(&lds[d6 * LDS_PITCH + lane], v6);
        atomicAdd(&lds[d7 * LDS_PITCH + lane], v7);
        if (lane == 0) {
            atomicAdd(&wsum[d0], w0); atomicAdd(&wsum[d1], w1);
            atomicAdd(&wsum[d2], w2); atomicAdd(&wsum[d3], w3);
            atomicAdd(&wsum[d4], w4); atomicAdd(&wsum[d5], w5);
            atomicAdd(&wsum[d6], w6); atomicAdd(&wsum[d7], w7);
        }
    }
    for (; e < ee; e += 4) {
        int2 p = pe[e];
        EDGE_DECODE(p, w, s, d)
        float v = w * x_in[(size_t)s * xstride + lane];
        atomicAdd(&lds[d * LDS_PITCH + lane], v);
        if (lane == 0) atomicAdd(&wsum[d], w);
    }
#undef EDGE_DECODE
    __syncthreads();

    // ---- Fixup: fold self-term + input BN affine (16 rows per wave) ----
#pragma unroll 4
    for (int nn = 0; nn < 16; ++nn) {
        int nl = wid * 16 + nn;
        int n = nbase + nl;
        float raw = lds[nl * LDS_PITCH + lane];
        float val = 0.0f;
        if (n < N_NODES) {
            float xn = x_in[(size_t)n * xstride + lane];   // coalesced 256B
            val = fmaf(sc_in, raw + xn, sh_in * (1.0f + wsum[nl]));
        }
        lds[nl * LDS_PITCH + lane] = val;
    }
    __syncthreads();

    // ---- Stage 1 GEMM: hidden = relu(xin @ W1^T + b1) ----
    float h[16];
#pragma unroll
    for (int jj = 0; jj < 16; ++jj) h[jj] = b1[wid * 16 + jj];
#pragma unroll 4
    for (int k = 0; k < DIM; ++k) {
        float xv = lds[lane * LDS_PITCH + k];
        const float* wr = W1T + k * DIM + wid * 16;   // uniform -> s_load
#pragma unroll
        for (int jj = 0; jj < 16; ++jj) h[jj] = fmaf(xv, wr[jj], h[jj]);
    }
#pragma unroll
    for (int jj = 0; jj < 16; ++jj) h[jj] = fmaxf(h[jj], 0.0f);
    __syncthreads();          // all lds (xin) reads done
#pragma unroll
    for (int jj = 0; jj < 16; ++jj) lds[lane * LDS_PITCH + wid * 16 + jj] = h[jj];
    __syncthreads();

    // ---- Stage 2 GEMM: o = relu(hidden @ W2^T + b2) ----
    float o[16];
#pragma unroll
    for (int jj = 0; jj < 16; ++jj) o[jj] = b2[wid * 16 + jj];
#pragma unroll 4
    for (int k = 0; k < DIM; ++k) {
        float hv = lds[lane * LDS_PITCH + k];
        const float* wr = W2T + k * DIM + wid * 16;
#pragma unroll
        for (int jj = 0; jj < 16; ++jj) o[jj] = fmaf(hv, wr[jj], o[jj]);
    }
    int n = nbase + lane;
    bool valid = (n < N_NODES);
#pragma unroll
    for (int jj = 0; jj < 16; ++jj) o[jj] = fmaxf(o[jj], 0.0f);
    if (valid) {
        float* orow = out + (size_t)n * OUTD + wid * 16;
#pragma unroll
        for (int jj = 0; jj < 16; jj += 4) {
            *(float4*)(orow + jj) = make_float4(o[jj], o[jj + 1], o[jj + 2], o[jj + 3]);
        }
    }

    // ---- BN stat partials: butterfly over 64 lanes; wave wid owns dims
    // [wid*16, wid*16+16). Non-atomic coalesced per-block store.
    float my_s = 0.0f, my_q = 0.0f;
#pragma unroll
    for (int jj = 0; jj < 16; ++jj) {
        float v = valid ? o[jj] : 0.0f;
        float vs = v, vq = v * v;
#pragma unroll
        for (int m = 1; m < 64; m <<= 1) {
            vs += __shfl_xor(vs, m);
            vq += __shfl_xor(vq, m);
        }
        if (lane == jj) { my_s = vs; my_q = vq; }
    }
    if (lane < 16) {
        size_t base = (size_t)blockIdx.x * 128 + wid * 16 + lane;
        pstat[base] = my_s;
        pstat[base + 64] = my_q;
    }
}

// ---------------------------------------------------------------------------
// Reduce per-block BN partials -> scale/shift (bn_prep folded).
__global__ void __launch_bounds__(256) reduce_stats(
    const float* __restrict__ pstat,
    const float* __restrict__ gamma, const float* __restrict__ beta,
    float* __restrict__ ss /* [128]: scale|shift */) {
    __shared__ double part[16][16];
    int b = blockIdx.x;            // 0..7
    int t = threadIdx.x;
    int slot = t & 15;             // 0..7 -> sum(d), 8..15 -> sumsq(d)
    int g = t >> 4;                // group 0..15
    int d = b * 8 + (slot & 7);
    int off = (slot < 8) ? 0 : 64;
    double s = 0.0;
    for (int blk = g; blk < NLBLK; blk += 16)
        s += (double)pstat[(size_t)blk * 128 + off + d];
    part[g][slot] = s;
    __syncthreads();
    if (t < 16) {
        double x = 0.0;
#pragma unroll
        for (int k = 0; k < 16; ++k) x += part[k][t];
        part[0][t] = x;            // column t only -> no hazard
    }
    __syncthreads();
    if (t < 8) {
        int dd = b * 8 + t;
        double mu = part[0][t] / (double)N_NODES;
        double var = part[0][8 + t] / (double)N_NODES - mu * mu;
        float inv = (float)(1.0 / sqrt(var + (double)BN_EPS));
        float sc = gamma[dd] * inv;
        ss[dd] = sc;
        ss[64 + dd] = beta[dd] - (float)mu * sc;
    }
}

// ---------------------------------------------------------------------------
// Final pass: apply BN affine to xs IN PLACE (all 3 layers at once) and
// add-pool per graph. Grid (512 graphs, 4 parts), block 192.
__global__ void bn_pool(float* __restrict__ xs,
                        const int* __restrict__ batch,
                        const float* __restrict__ ss /* [3][128] */,
                        float* __restrict__ pooled) {
    int g = blockIdx.x;
    int part = blockIdx.y;   // 0..3
    int d = threadIdx.x;     // 0..191
    int l = d >> 6, dd = d & 63;
    float sc = ss[l * 128 + dd];
    float sh = ss[l * 128 + 64 + dd];
    int start, end;
    {
        int lo = 0, hi = N_NODES;
        while (lo < hi) { int m = (lo + hi) >> 1; if (batch[m] < g) lo = m + 1; else hi = m; }
        start = lo;
    }
    {
        int lo = start, hi = N_NODES;
        while (lo < hi) { int m = (lo + hi) >> 1; if (batch[m] <= g) lo = m + 1; else hi = m; }
        end = lo;
    }
    float acc = 0.0f;
    for (int n = start + part; n < end; n += 4) {
        float* p = xs + (size_t)n * OUTD + d;
        float v = fmaf(*p, sc, sh);
        *p = v;
        acc += v;
    }
    atomicAdd(&pooled[(size_t)g * OUTD + d], acc);
}

// ---------------------------------------------------------------------------
extern "C" void kernel_launch(void* const* d_in, const int* in_sizes, int n_in,
                              void* d_out, int out_size, void* d_ws, size_t ws_size,
                              hipStream_t stream) {
    const float* x0    = (const float*)d_in[0];
    const int*   ei    = (const int*)d_in[1];
    const float* ew    = (const float*)d_in[2];
    const int*   batch = (const int*)d_in[3];
    const float* W1    = (const float*)d_in[5];
    const float* b1    = (const float*)d_in[6];
    const float* W2    = (const float*)d_in[7];
    const float* b2    = (const float*)d_in[8];
    const float* gamma = (const float*)d_in[9];
    const float* beta  = (const float*)d_in[10];

    float* pooled = (float*)d_out;                      // [512, 192]
    float* xs     = pooled + (size_t)N_GRAPHS * OUTD;   // [100000, 192]

    const int* src = ei;
    const int* dst = ei + N_EDGES;

    // Workspace layout (~21.5 MB):
    // pe[E] | pp[E] | seg[N+4] | hist[NPBLK*NBUK] | base[NPBLK*NBUK]
    // | tot[NBUK+4] | bstart[NBUK+4] | W1T | W2T | idaff | ss | pstat
    int2*  pe     = (int2*)d_ws;
    int2*  pp     = pe + N_EDGES;
    int*   seg    = (int*)(pp + N_EDGES);
    int*   hist   = seg + N_NODES + 4;
    int*   pbase  = hist + (size_t)NPBLK * NBUK;
    int*   tot    = pbase + (size_t)NPBLK * NBUK;
    int*   bstart = tot + NBUK + 4;
    float* W1T    = (float*)(bstart + NBUK + 4);
    float* W2T    = W1T + N_LAYERS * DIM * DIM;
    float* idaff  = W2T + N_LAYERS * DIM * DIM;    // 128 floats
    float* ss     = idaff + 128;                   // 3*128 floats
    float* pstat  = ss + N_LAYERS * 128;           // NLBLK*128 floats

    transpose_w<<<(N_LAYERS * DIM * DIM + 255) / 256, 256, 0, stream>>>(
        W1, W2, W1T, W2T, idaff);

    // Two-level binning: contention-free partition -> per-bucket CSR.
    hipMemsetAsync(tot, 0, (NBUK + 4) * sizeof(int), stream);
    part_hist<<<NPBLK, 256, 0, stream>>>(dst, hist, tot);
    scan196<<<1, 256, 0, stream>>>(tot, bstart);
    base_fill<<<NBUK, 256, 0, stream>>>(hist, bstart, pbase);
    part_scatter<<<NPBLK, 256, 0, stream>>>(src, dst, ew, pbase, pp);
    csr_build<<<NBUK, 256, 0, stream>>>(pp, bstart, seg, pe);

    for (int i = 0; i < N_LAYERS; ++i) {
        const float* xin = (i == 0) ? x0 : (xs + (size_t)(i - 1) * DIM);
        int xstride = (i == 0) ? DIM : OUTD;
        const float* affine = (i == 0) ? idaff : (ss + (size_t)(i - 1) * 128);

        layer_kernel<<<NLBLK, 256, 0, stream>>>(
            xin, xstride, seg, pe, affine,
            W1T + (size_t)i * DIM * DIM, b1 + (size_t)i * DIM,
            W2T + (size_t)i * DIM * DIM, b2 + (size_t)i * DIM,
            xs + (size_t)i * DIM, pstat);

        reduce_stats<<<8, 256, 0, stream>>>(
            pstat, gamma + (size_t)i * DIM, beta + (size_t)i * DIM,
            ss + (size_t)i * 128);
    }

    hipMemsetAsync(pooled, 0, (size_t)N_GRAPHS * OUTD * sizeof(float), stream);
    dim3 pgrid(N_GRAPHS, 4);
    bn_pool<<<pgrid, OUTD, 0, stream>>>(xs, batch, ss, pooled);
}

// Round 4
// 602.566 us; speedup vs baseline: 2.9217x; 2.9217x over previous
//
#include <hip/hip_runtime.h>

#define N_NODES 100000
#define N_EDGES 1200000
#define DIM     64
#define N_LAYERS 3
#define N_GRAPHS 512
#define OUTD    192   // 3 * 64, concat layout
#define BN_EPS  1e-5f

#define NPB 64            // nodes per block in layer_kernel
#define LDS_PITCH 65      // +1 pad -> 2-way bank aliasing only (free)
#define NLBLK ((N_NODES + NPB - 1) / NPB)                 // 1563

// ---- two-level binning geometry ----
#define BSHIFT 9
#define BUCK_NODES (1 << BSHIFT)                          // 512 nodes / bucket
#define NBUK ((N_NODES + BUCK_NODES - 1) / BUCK_NODES)    // 196
#define EPB 4096                                          // edges per partition block
#define NPBLK ((N_EDGES + EPB - 1) / EPB)                 // 293

// ---------------------------------------------------------------------------
// Transpose W1/W2 (per layer): WT[l][k][j] = W[l][j][k]. Also writes the
// identity affine block (scale=1, shift=0) used by layer 0.
__global__ void transpose_w(const float* __restrict__ W1, const float* __restrict__ W2,
                            float* __restrict__ W1T, float* __restrict__ W2T,
                            float* __restrict__ idaff) {
    int idx = blockIdx.x * blockDim.x + threadIdx.x;  // L*64*64
    if (idx < 128) idaff[idx] = (idx < 64) ? 1.0f : 0.0f;
    if (idx >= N_LAYERS * DIM * DIM) return;
    int l = idx >> 12;
    int r = idx & 4095;
    int j = r >> 6;
    int k = r & 63;
    int dstp = (l << 12) + k * DIM + j;
    W1T[dstp] = W1[idx];
    W2T[dstp] = W2[idx];
}

// ---------------------------------------------------------------------------
// Phase A: per-block bucket histogram (LDS atomics) + global bucket totals
// (196 addresses x 293 adds each, spread over time -> negligible contention).
__global__ void __launch_bounds__(256) part_hist(const int* __restrict__ dst,
                                                 int* __restrict__ hist,
                                                 int* __restrict__ tot) {
    __shared__ int h[NBUK];
    int t = threadIdx.x;
    if (t < NBUK) h[t] = 0;
    __syncthreads();
    int base = blockIdx.x * EPB;
    for (int i = t; i < EPB; i += 256) {
        int e = base + i;
        if (e < N_EDGES) atomicAdd(&h[dst[e] >> BSHIFT], 1);
    }
    __syncthreads();
    if (t < NBUK) {
        int v = h[t];
        hist[blockIdx.x * NBUK + t] = v;
        if (v) atomicAdd(&tot[t], v);
    }
}

// ---------------------------------------------------------------------------
// Phase B1: scan 196 bucket totals -> bucket starts. One tiny block.
__global__ void __launch_bounds__(256) scan196(const int* __restrict__ tot,
                                               int* __restrict__ bstart) {
    __shared__ int lds[256];
    int t = threadIdx.x;
    int v = (t < NBUK) ? tot[t] : 0;
    lds[t] = v;
    __syncthreads();
    for (int o = 1; o < 256; o <<= 1) {
        int add = (t >= o) ? lds[t - o] : 0;
        __syncthreads();
        lds[t] += add;
        __syncthreads();
    }
    if (t < NBUK) bstart[t] = lds[t] - v;   // exclusive
    if (t == 0) bstart[NBUK] = N_EDGES;
}

// ---------------------------------------------------------------------------
// Phase B2: per-(block,bucket) bases. Block b scans hist column b (293
// entries) in LDS -- parallel loads, parallel scan.
__global__ void __launch_bounds__(256) base_fill(const int* __restrict__ hist,
                                                 const int* __restrict__ bstart,
                                                 int* __restrict__ base) {
    __shared__ int c[512];
    __shared__ int ssum[256];
    int b = blockIdx.x, t = threadIdx.x;
    c[t] = (t < NPBLK) ? hist[t * NBUK + b] : 0;
    c[t + 256] = (t + 256 < NPBLK) ? hist[(t + 256) * NBUK + b] : 0;
    __syncthreads();
    int c0 = c[2 * t], c1 = c[2 * t + 1];
    int ps = c0 + c1;
    ssum[t] = ps;
    __syncthreads();
    int v = ps;
    for (int o = 1; o < 256; o <<= 1) {
        int add = (t >= o) ? ssum[t - o] : 0;
        __syncthreads();
        ssum[t] += add;
        __syncthreads();
    }
    int excl = ssum[t] - v + bstart[b];     // exclusive over pairs + bucket base
    if (2 * t < NPBLK)     base[(2 * t) * NBUK + b] = excl;
    if (2 * t + 1 < NPBLK) base[(2 * t + 1) * NBUK + b] = excl + c0;
}

// ---------------------------------------------------------------------------
// Phase C: scatter edges into bucket-partitioned order. Each (block,bucket)
// range is disjoint (deterministic bases), LDS cursors only. Packs
// (src | dstLocal<<17, w) into one int2 (src<2^17, dstLocal<2^9).
__global__ void __launch_bounds__(256) part_scatter(
        const int* __restrict__ src, const int* __restrict__ dst,
        const float* __restrict__ ew, const int* __restrict__ base,
        int2* __restrict__ pp) {
    __shared__ int cur[NBUK];
    int t = threadIdx.x;
    if (t < NBUK) cur[t] = base[blockIdx.x * NBUK + t];
    __syncthreads();
    int bb = blockIdx.x * EPB;
    for (int i = t; i < EPB; i += 256) {
        int e = bb + i;
        if (e < N_EDGES) {
            int d = dst[e];
            int bk = d >> BSHIFT;
            int pos = atomicAdd(&cur[bk], 1);
            int dl = d & (BUCK_NODES - 1);
            pp[pos] = make_int2(src[e] | (dl << 17), __float_as_int(ew[e]));
        }
    }
}

// ---------------------------------------------------------------------------
// Phase D: per-bucket counting sort -> CSR. All scattered writes confined to
// the bucket's ~48KB edge window (L2-resident, dense writebacks).
__global__ void __launch_bounds__(256) csr_build(
        const int2* __restrict__ pp, const int* __restrict__ bstart,
        int* __restrict__ seg, int2* __restrict__ pe) {
    __shared__ int cnt[BUCK_NODES];
    __shared__ int ssum[256];
    int b = blockIdx.x, t = threadIdx.x;
    int ebeg = bstart[b], eend = bstart[b + 1];
    cnt[t] = 0;
    cnt[t + 256] = 0;
    __syncthreads();
    for (int e = ebeg + t; e < eend; e += 256)
        atomicAdd(&cnt[pp[e].x >> 17], 1);
    __syncthreads();
    // scan over 512 counts: thread t owns pair (2t, 2t+1)
    int c0 = cnt[2 * t], c1 = cnt[2 * t + 1];
    int ps = c0 + c1;
    ssum[t] = ps;
    __syncthreads();
    int v = ps;
    for (int o = 1; o < 256; o <<= 1) {
        int add = (t >= o) ? ssum[t - o] : 0;
        __syncthreads();
        ssum[t] += add;
        __syncthreads();
    }
    int excl = ssum[t] - v;           // exclusive over pairs
    int o0 = ebeg + excl;
    int o1 = o0 + c0;
    int n0 = (b << BSHIFT) + 2 * t;
    if (n0 < N_NODES) seg[n0] = o0;
    if (n0 + 1 < N_NODES) seg[n0 + 1] = o1;
    __syncthreads();                  // all cnt reads (c0,c1) retired
    cnt[2 * t] = o0;                  // reuse as cursors (global positions)
    cnt[2 * t + 1] = o1;
    __syncthreads();
    for (int e = ebeg + t; e < eend; e += 256) {
        int2 p = pp[e];
        int pos = atomicAdd(&cnt[p.x >> 17], 1);
        pe[pos] = make_int2(p.x & 0x1FFFF, p.y);   // plain (src, w)
    }
    if (b == 0 && t == 0) seg[N_NODES] = N_EDGES;
}

// ---------------------------------------------------------------------------
// Fused layer (CSR, node-parallel gather with PAIR INTERLEAVE):
// R1 (best measured, 80.5us) was latency-bound: per node ~3 sequential
// rounds of 4 in-flight loads + 2 scalar seg loads between nodes.
// R4 changes (no occupancy cost, no extra LDS traffic):
//  - wave preloads its 17 CSR offsets once; per-node beg/end via __shfl.
//  - 16 nodes processed as 8 pairs, both nodes' 4-unrolled loops
//    interleaved -> 8 independent loads in flight in the common phase.
// All branches wave-uniform; per-node summation order unchanged.
__global__ void __launch_bounds__(256) layer_kernel(
    const float* __restrict__ x_in, int xstride,
    const int* __restrict__ seg,     // CSR offsets (N+1)
    const int2* __restrict__ pe,     // (src, w)
    const float* __restrict__ affine /* [128]: scale|shift of input */,
    const float* __restrict__ W1T, const float* __restrict__ b1,
    const float* __restrict__ W2T, const float* __restrict__ b2,
    float* __restrict__ out /* xs base + layer*64, row stride OUTD */,
    float* __restrict__ pstat /* [NLBLK][128]: sum|sumsq partials */) {
    __shared__ float lds[NPB * LDS_PITCH];
    int t = threadIdx.x;
    int lane = t & 63;
    int wid = __builtin_amdgcn_readfirstlane(t >> 6);   // wave id 0..3, SGPR
    int nbase = blockIdx.x * NPB;

    float sc_in = affine[lane];          // coalesced 256B, once
    float sh_in = affine[64 + lane];

    // wave's 17 seg values in lanes 0..16 (one coalesced load)
    int segi = nbase + wid * 16 + lane;
    if (segi > N_NODES) segi = N_NODES;
    int segv = (lane < 17) ? seg[segi] : 0;

#define STEP4(EIDX, A0, A1, A2, A3, WS)                                        \
    {                                                                          \
        int2 q0 = pe[EIDX];     int2 q1 = pe[(EIDX) + 1];                      \
        int2 q2 = pe[(EIDX) + 2]; int2 q3 = pe[(EIDX) + 3];                    \
        float w0 = __int_as_float(q0.y), w1 = __int_as_float(q1.y);            \
        float w2 = __int_as_float(q2.y), w3 = __int_as_float(q3.y);            \
        A0 = fmaf(w0, x_in[(size_t)q0.x * xstride + lane], A0);                \
        A1 = fmaf(w1, x_in[(size_t)q1.x * xstride + lane], A1);                \
        A2 = fmaf(w2, x_in[(size_t)q2.x * xstride + lane], A2);                \
        A3 = fmaf(w3, x_in[(size_t)q3.x * xstride + lane], A3);                \
        WS += (w0 + w1) + (w2 + w3);                                           \
    }
#define STEP1(EIDX, A1, WS)                                                    \
    {                                                                          \
        int2 q = pe[EIDX];                                                     \
        float w = __int_as_float(q.y);                                         \
        A1 = fmaf(w, x_in[(size_t)q.x * xstride + lane], A1);                  \
        WS += w;                                                               \
    }

    // ---- Phase 1: gather, 8 node-pairs per wave ----
    for (int qq = 0; qq < 8; ++qq) {
        int nlA = wid * 16 + 2 * qq;
        int nA = nbase + nlA;
        int bA = __shfl(segv, 2 * qq);
        int mB = __shfl(segv, 2 * qq + 1);   // endA == begB
        int eE = __shfl(segv, 2 * qq + 2);
        bool vA = (nA < N_NODES);
        bool vB = (nA + 1 < N_NODES);
        // self terms first (2 more loads in flight)
        float aA0 = vA ? x_in[(size_t)nA * xstride + lane] : 0.0f;
        float aB0 = vB ? x_in[(size_t)(nA + 1) * xstride + lane] : 0.0f;
        float aA1 = 0.0f, aA2 = 0.0f, aA3 = 0.0f, wsA = 0.0f;
        float aB1 = 0.0f, aB2 = 0.0f, aB3 = 0.0f, wsB = 0.0f;
        int ea = bA, eb = mB;
        // interleaved common phase: 8 independent loads in flight
        while (ea + 4 <= mB && eb + 4 <= eE) {
            STEP4(ea, aA0, aA1, aA2, aA3, wsA)
            STEP4(eb, aB0, aB1, aB2, aB3, wsB)
            ea += 4; eb += 4;
        }
        // drain A
        for (; ea + 4 <= mB; ea += 4) STEP4(ea, aA0, aA1, aA2, aA3, wsA)
        for (; ea < mB; ++ea)         STEP1(ea, aA1, wsA)
        // drain B
        for (; eb + 4 <= eE; eb += 4) STEP4(eb, aB0, aB1, aB2, aB3, wsB)
        for (; eb < eE; ++eb)         STEP1(eb, aB1, wsB)
        float sA = (aA0 + aA1) + (aA2 + aA3);
        float sB = (aB0 + aB1) + (aB2 + aB3);
        lds[nlA * LDS_PITCH + lane] =
            vA ? fmaf(sc_in, sA, sh_in * (1.0f + wsA)) : 0.0f;
        lds[(nlA + 1) * LDS_PITCH + lane] =
            vB ? fmaf(sc_in, sB, sh_in * (1.0f + wsB)) : 0.0f;
    }
#undef STEP4
#undef STEP1
    __syncthreads();

    // ---- Stage 1 GEMM: hidden = relu(xin @ W1^T + b1) ----
    float h[16];
#pragma unroll
    for (int jj = 0; jj < 16; ++jj) h[jj] = b1[wid * 16 + jj];
#pragma unroll 4
    for (int k = 0; k < DIM; ++k) {
        float xv = lds[lane * LDS_PITCH + k];
        const float* wr = W1T + k * DIM + wid * 16;   // uniform -> s_load
#pragma unroll
        for (int jj = 0; jj < 16; ++jj) h[jj] = fmaf(xv, wr[jj], h[jj]);
    }
#pragma unroll
    for (int jj = 0; jj < 16; ++jj) h[jj] = fmaxf(h[jj], 0.0f);
    __syncthreads();          // all lds (xin) reads done
#pragma unroll
    for (int jj = 0; jj < 16; ++jj) lds[lane * LDS_PITCH + wid * 16 + jj] = h[jj];
    __syncthreads();

    // ---- Stage 2 GEMM: o = relu(hidden @ W2^T + b2) ----
    float o[16];
#pragma unroll
    for (int jj = 0; jj < 16; ++jj) o[jj] = b2[wid * 16 + jj];
#pragma unroll 4
    for (int k = 0; k < DIM; ++k) {
        float hv = lds[lane * LDS_PITCH + k];
        const float* wr = W2T + k * DIM + wid * 16;
#pragma unroll
        for (int jj = 0; jj < 16; ++jj) o[jj] = fmaf(hv, wr[jj], o[jj]);
    }
    int n = nbase + lane;
    bool valid = (n < N_NODES);
#pragma unroll
    for (int jj = 0; jj < 16; ++jj) o[jj] = fmaxf(o[jj], 0.0f);
    if (valid) {
        float* orow = out + (size_t)n * OUTD + wid * 16;
#pragma unroll
        for (int jj = 0; jj < 16; jj += 4) {
            *(float4*)(orow + jj) = make_float4(o[jj], o[jj + 1], o[jj + 2], o[jj + 3]);
        }
    }

    // ---- BN stat partials: butterfly over 64 lanes; wave wid owns dims
    // [wid*16, wid*16+16). Non-atomic coalesced per-block store.
    float my_s = 0.0f, my_q = 0.0f;
#pragma unroll
    for (int jj = 0; jj < 16; ++jj) {
        float v = valid ? o[jj] : 0.0f;
        float vs = v, vq = v * v;
#pragma unroll
        for (int m = 1; m < 64; m <<= 1) {
            vs += __shfl_xor(vs, m);
            vq += __shfl_xor(vq, m);
        }
        if (lane == jj) { my_s = vs; my_q = vq; }
    }
    if (lane < 16) {
        size_t base = (size_t)blockIdx.x * 128 + wid * 16 + lane;
        pstat[base] = my_s;
        pstat[base + 64] = my_q;
    }
}

// ---------------------------------------------------------------------------
// Reduce per-block BN partials -> scale/shift (bn_prep folded).
__global__ void __launch_bounds__(256) reduce_stats(
    const float* __restrict__ pstat,
    const float* __restrict__ gamma, const float* __restrict__ beta,
    float* __restrict__ ss /* [128]: scale|shift */) {
    __shared__ double part[16][16];
    int b = blockIdx.x;            // 0..7
    int t = threadIdx.x;
    int slot = t & 15;             // 0..7 -> sum(d), 8..15 -> sumsq(d)
    int g = t >> 4;                // group 0..15
    int d = b * 8 + (slot & 7);
    int off = (slot < 8) ? 0 : 64;
    double s = 0.0;
    for (int blk = g; blk < NLBLK; blk += 16)
        s += (double)pstat[(size_t)blk * 128 + off + d];
    part[g][slot] = s;
    __syncthreads();
    if (t < 16) {
        double x = 0.0;
#pragma unroll
        for (int k = 0; k < 16; ++k) x += part[k][t];
        part[0][t] = x;            // column t only -> no hazard
    }
    __syncthreads();
    if (t < 8) {
        int dd = b * 8 + t;
        double mu = part[0][t] / (double)N_NODES;
        double var = part[0][8 + t] / (double)N_NODES - mu * mu;
        float inv = (float)(1.0 / sqrt(var + (double)BN_EPS));
        float sc = gamma[dd] * inv;
        ss[dd] = sc;
        ss[64 + dd] = beta[dd] - (float)mu * sc;
    }
}

// ---------------------------------------------------------------------------
// Final pass: apply BN affine to xs IN PLACE (all 3 layers at once) and
// add-pool per graph. Grid (512 graphs, 4 parts), block 192.
__global__ void bn_pool(float* __restrict__ xs,
                        const int* __restrict__ batch,
                        const float* __restrict__ ss /* [3][128] */,
                        float* __restrict__ pooled) {
    int g = blockIdx.x;
    int part = blockIdx.y;   // 0..3
    int d = threadIdx.x;     // 0..191
    int l = d >> 6, dd = d & 63;
    float sc = ss[l * 128 + dd];
    float sh = ss[l * 128 + 64 + dd];
    int start, end;
    {
        int lo = 0, hi = N_NODES;
        while (lo < hi) { int m = (lo + hi) >> 1; if (batch[m] < g) lo = m + 1; else hi = m; }
        start = lo;
    }
    {
        int lo = start, hi = N_NODES;
        while (lo < hi) { int m = (lo + hi) >> 1; if (batch[m] <= g) lo = m + 1; else hi = m; }
        end = lo;
    }
    float acc = 0.0f;
    for (int n = start + part; n < end; n += 4) {
        float* p = xs + (size_t)n * OUTD + d;
        float v = fmaf(*p, sc, sh);
        *p = v;
        acc += v;
    }
    atomicAdd(&pooled[(size_t)g * OUTD + d], acc);
}

// ---------------------------------------------------------------------------
extern "C" void kernel_launch(void* const* d_in, const int* in_sizes, int n_in,
                              void* d_out, int out_size, void* d_ws, size_t ws_size,
                              hipStream_t stream) {
    const float* x0    = (const float*)d_in[0];
    const int*   ei    = (const int*)d_in[1];
    const float* ew    = (const float*)d_in[2];
    const int*   batch = (const int*)d_in[3];
    const float* W1    = (const float*)d_in[5];
    const float* b1    = (const float*)d_in[6];
    const float* W2    = (const float*)d_in[7];
    const float* b2    = (const float*)d_in[8];
    const float* gamma = (const float*)d_in[9];
    const float* beta  = (const float*)d_in[10];

    float* pooled = (float*)d_out;                      // [512, 192]
    float* xs     = pooled + (size_t)N_GRAPHS * OUTD;   // [100000, 192]

    const int* src = ei;
    const int* dst = ei + N_EDGES;

    // Workspace layout (~21.5 MB):
    // pe[E] | pp[E] | seg[N+4] | hist[NPBLK*NBUK] | base[NPBLK*NBUK]
    // | tot[NBUK+4] | bstart[NBUK+4] | W1T | W2T | idaff | ss | pstat
    int2*  pe     = (int2*)d_ws;
    int2*  pp     = pe + N_EDGES;
    int*   seg    = (int*)(pp + N_EDGES);
    int*   hist   = seg + N_NODES + 4;
    int*   pbase  = hist + (size_t)NPBLK * NBUK;
    int*   tot    = pbase + (size_t)NPBLK * NBUK;
    int*   bstart = tot + NBUK + 4;
    float* W1T    = (float*)(bstart + NBUK + 4);
    float* W2T    = W1T + N_LAYERS * DIM * DIM;
    float* idaff  = W2T + N_LAYERS * DIM * DIM;    // 128 floats
    float* ss     = idaff + 128;                   // 3*128 floats
    float* pstat  = ss + N_LAYERS * 128;           // NLBLK*128 floats

    transpose_w<<<(N_LAYERS * DIM * DIM + 255) / 256, 256, 0, stream>>>(
        W1, W2, W1T, W2T, idaff);

    // Two-level binning: contention-free partition -> per-bucket CSR.
    hipMemsetAsync(tot, 0, (NBUK + 4) * sizeof(int), stream);
    part_hist<<<NPBLK, 256, 0, stream>>>(dst, hist, tot);
    scan196<<<1, 256, 0, stream>>>(tot, bstart);
    base_fill<<<NBUK, 256, 0, stream>>>(hist, bstart, pbase);
    part_scatter<<<NPBLK, 256, 0, stream>>>(src, dst, ew, pbase, pp);
    csr_build<<<NBUK, 256, 0, stream>>>(pp, bstart, seg, pe);

    for (int i = 0; i < N_LAYERS; ++i) {
        const float* xin = (i == 0) ? x0 : (xs + (size_t)(i - 1) * DIM);
        int xstride = (i == 0) ? DIM : OUTD;
        const float* affine = (i == 0) ? idaff : (ss + (size_t)(i - 1) * 128);

        layer_kernel<<<NLBLK, 256, 0, stream>>>(
            xin, xstride, seg, pe, affine,
            W1T + (size_t)i * DIM * DIM, b1 + (size_t)i * DIM,
            W2T + (size_t)i * DIM * DIM, b2 + (size_t)i * DIM,
            xs + (size_t)i * DIM, pstat);

        reduce_stats<<<8, 256, 0, stream>>>(
            pstat, gamma + (size_t)i * DIM, beta + (size_t)i * DIM,
            ss + (size_t)i * 128);
    }

    hipMemsetAsync(pooled, 0, (size_t)N_GRAPHS * OUTD * sizeof(float), stream);
    dim3 pgrid(N_GRAPHS, 4);
    bn_pool<<<pgrid, OUTD, 0, stream>>>(xs, batch, ss, pooled);
}

// Round 5
// 537.945 us; speedup vs baseline: 3.2726x; 1.1201x over previous
//
#include <hip/hip_runtime.h>

#define N_NODES 100000
#define N_EDGES 1200000
#define DIM     64
#define N_LAYERS 3
#define N_GRAPHS 512
#define OUTD    192   // 3 * 64, concat layout
#define BN_EPS  1e-5f

#define NPB 64            // nodes per block in layer_kernel
#define LDS_PITCH 65      // +1 pad -> 2-way bank aliasing only (free)
#define NLBLK ((N_NODES + NPB - 1) / NPB)                 // 1563

// ---- two-level binning geometry ----
#define BSHIFT 9
#define BUCK_NODES (1 << BSHIFT)                          // 512 nodes / bucket
#define NBUK ((N_NODES + BUCK_NODES - 1) / BUCK_NODES)    // 196
#define EPB 4096                                          // edges per partition block
#define NPBLK ((N_EDGES + EPB - 1) / EPB)                 // 293

// ---------------------------------------------------------------------------
// Transpose W1/W2 (per layer): WT[l][k][j] = W[l][j][k]. Also writes the
// identity affine block (scale=1, shift=0) used by layer 0.
__global__ void transpose_w(const float* __restrict__ W1, const float* __restrict__ W2,
                            float* __restrict__ W1T, float* __restrict__ W2T,
                            float* __restrict__ idaff) {
    int idx = blockIdx.x * blockDim.x + threadIdx.x;  // L*64*64
    if (idx < 128) idaff[idx] = (idx < 64) ? 1.0f : 0.0f;
    if (idx >= N_LAYERS * DIM * DIM) return;
    int l = idx >> 12;
    int r = idx & 4095;
    int j = r >> 6;
    int k = r & 63;
    int dstp = (l << 12) + k * DIM + j;
    W1T[dstp] = W1[idx];
    W2T[dstp] = W2[idx];
}

// ---------------------------------------------------------------------------
// Phase A: per-block bucket histogram (LDS atomics) + global bucket totals
// (196 addresses x 293 adds each, spread over time -> negligible contention).
__global__ void __launch_bounds__(256) part_hist(const int* __restrict__ dst,
                                                 int* __restrict__ hist,
                                                 int* __restrict__ tot) {
    __shared__ int h[NBUK];
    int t = threadIdx.x;
    if (t < NBUK) h[t] = 0;
    __syncthreads();
    int base = blockIdx.x * EPB;
    for (int i = t; i < EPB; i += 256) {
        int e = base + i;
        if (e < N_EDGES) atomicAdd(&h[dst[e] >> BSHIFT], 1);
    }
    __syncthreads();
    if (t < NBUK) {
        int v = h[t];
        hist[blockIdx.x * NBUK + t] = v;
        if (v) atomicAdd(&tot[t], v);
    }
}

// ---------------------------------------------------------------------------
// Phase B1: scan 196 bucket totals -> bucket starts. One tiny block.
__global__ void __launch_bounds__(256) scan196(const int* __restrict__ tot,
                                               int* __restrict__ bstart) {
    __shared__ int lds[256];
    int t = threadIdx.x;
    int v = (t < NBUK) ? tot[t] : 0;
    lds[t] = v;
    __syncthreads();
    for (int o = 1; o < 256; o <<= 1) {
        int add = (t >= o) ? lds[t - o] : 0;
        __syncthreads();
        lds[t] += add;
        __syncthreads();
    }
    if (t < NBUK) bstart[t] = lds[t] - v;   // exclusive
    if (t == 0) bstart[NBUK] = N_EDGES;
}

// ---------------------------------------------------------------------------
// Phase B2: per-(block,bucket) bases. Block b scans hist column b (293
// entries) in LDS -- parallel loads, parallel scan.
__global__ void __launch_bounds__(256) base_fill(const int* __restrict__ hist,
                                                 const int* __restrict__ bstart,
                                                 int* __restrict__ base) {
    __shared__ int c[512];
    __shared__ int ssum[256];
    int b = blockIdx.x, t = threadIdx.x;
    c[t] = (t < NPBLK) ? hist[t * NBUK + b] : 0;
    c[t + 256] = (t + 256 < NPBLK) ? hist[(t + 256) * NBUK + b] : 0;
    __syncthreads();
    int c0 = c[2 * t], c1 = c[2 * t + 1];
    int ps = c0 + c1;
    ssum[t] = ps;
    __syncthreads();
    int v = ps;
    for (int o = 1; o < 256; o <<= 1) {
        int add = (t >= o) ? ssum[t - o] : 0;
        __syncthreads();
        ssum[t] += add;
        __syncthreads();
    }
    int excl = ssum[t] - v + bstart[b];     // exclusive over pairs + bucket base
    if (2 * t < NPBLK)     base[(2 * t) * NBUK + b] = excl;
    if (2 * t + 1 < NPBLK) base[(2 * t + 1) * NBUK + b] = excl + c0;
}

// ---------------------------------------------------------------------------
// Phase C: scatter edges into bucket-partitioned order. Each (block,bucket)
// range is disjoint (deterministic bases), LDS cursors only. Packs
// (src | dstLocal<<17, w) into one int2 (src<2^17, dstLocal<2^9).
__global__ void __launch_bounds__(256) part_scatter(
        const int* __restrict__ src, const int* __restrict__ dst,
        const float* __restrict__ ew, const int* __restrict__ base,
        int2* __restrict__ pp) {
    __shared__ int cur[NBUK];
    int t = threadIdx.x;
    if (t < NBUK) cur[t] = base[blockIdx.x * NBUK + t];
    __syncthreads();
    int bb = blockIdx.x * EPB;
    for (int i = t; i < EPB; i += 256) {
        int e = bb + i;
        if (e < N_EDGES) {
            int d = dst[e];
            int bk = d >> BSHIFT;
            int pos = atomicAdd(&cur[bk], 1);
            int dl = d & (BUCK_NODES - 1);
            pp[pos] = make_int2(src[e] | (dl << 17), __float_as_int(ew[e]));
        }
    }
}

// ---------------------------------------------------------------------------
// Phase D: per-bucket counting sort -> CSR. All scattered writes confined to
// the bucket's ~48KB edge window (L2-resident, dense writebacks).
__global__ void __launch_bounds__(256) csr_build(
        const int2* __restrict__ pp, const int* __restrict__ bstart,
        int* __restrict__ seg, int2* __restrict__ pe) {
    __shared__ int cnt[BUCK_NODES];
    __shared__ int ssum[256];
    int b = blockIdx.x, t = threadIdx.x;
    int ebeg = bstart[b], eend = bstart[b + 1];
    cnt[t] = 0;
    cnt[t + 256] = 0;
    __syncthreads();
    for (int e = ebeg + t; e < eend; e += 256)
        atomicAdd(&cnt[pp[e].x >> 17], 1);
    __syncthreads();
    // scan over 512 counts: thread t owns pair (2t, 2t+1)
    int c0 = cnt[2 * t], c1 = cnt[2 * t + 1];
    int ps = c0 + c1;
    ssum[t] = ps;
    __syncthreads();
    int v = ps;
    for (int o = 1; o < 256; o <<= 1) {
        int add = (t >= o) ? ssum[t - o] : 0;
        __syncthreads();
        ssum[t] += add;
        __syncthreads();
    }
    int excl = ssum[t] - v;           // exclusive over pairs
    int o0 = ebeg + excl;
    int o1 = o0 + c0;
    int n0 = (b << BSHIFT) + 2 * t;
    if (n0 < N_NODES) seg[n0] = o0;
    if (n0 + 1 < N_NODES) seg[n0 + 1] = o1;
    __syncthreads();                  // all cnt reads (c0,c1) retired
    cnt[2 * t] = o0;                  // reuse as cursors (global positions)
    cnt[2 * t + 1] = o1;
    __syncthreads();
    for (int e = ebeg + t; e < eend; e += 256) {
        int2 p = pp[e];
        int pos = atomicAdd(&cnt[p.x >> 17], 1);
        pe[pos] = make_int2(p.x & 0x1FFFF, p.y);   // plain (src, w)
    }
    if (b == 0 && t == 0) seg[N_NODES] = N_EDGES;
}

// ---------------------------------------------------------------------------
// Fused layer (CSR, FLOAT4-LANE gather): R1-R4 showed the gather is latency/
// issue bound with perf ~ occupancy at VALUBusy 27%. New load economics:
// lane = (slot=lane>>4, col=lane&15); each quarter-wave fetches one edge's
// full 256B row as dwordx4 -> ONE load instruction retires 4 edges (1KB)
// vs 4 instructions per edge before; 1/4 the address VALU; per-node loop is
// ceil(deg/16) iterations of 4 independent masked loads (usually 1, no
// loop-carried chain). Cross-slot reduce = 10 shuffles/node. LDS stores
// scalar (pitch 65 stays conflict-free for the GEMM reads).
__global__ void __launch_bounds__(256) layer_kernel(
    const float* __restrict__ x_in, int xstride,
    const int* __restrict__ seg,     // CSR offsets (N+1)
    const int2* __restrict__ pe,     // (src, w)
    const float* __restrict__ affine /* [128]: scale|shift of input */,
    const float* __restrict__ W1T, const float* __restrict__ b1,
    const float* __restrict__ W2T, const float* __restrict__ b2,
    float* __restrict__ out /* xs base + layer*64, row stride OUTD */,
    float* __restrict__ pstat /* [NLBLK][128]: sum|sumsq partials */) {
    __shared__ float lds[NPB * LDS_PITCH];
    int t = threadIdx.x;
    int lane = t & 63;
    int wid = __builtin_amdgcn_readfirstlane(t >> 6);   // wave id 0..3, SGPR
    int nbase = blockIdx.x * NPB;

    int slot = lane >> 4;            // 0..3: which edge of a 4-group
    int col  = lane & 15;            // which float4 of the row
    const float4* aff4 = (const float4*)affine;
    float4 sc4 = aff4[col];          // scale for cols 4c..4c+3
    float4 sh4 = aff4[16 + col];     // shift

    // ---- Phase 1: gather (16 nodes per wave, node id wave-uniform) ----
    for (int nn = 0; nn < 16; ++nn) {
        int nl = wid * 16 + nn;
        int n = nbase + nl;
        float ax = 0.f, ay = 0.f, az = 0.f, aw = 0.f, wsa = 0.f;
        float bx = 0.f, by = 0.f, bz = 0.f, bw = 0.f, wsb = 0.f;
        if (n < N_NODES) {
            int beg = seg[n];
            int end = seg[n + 1];
#define GBODY(EI, X, Y, Z, W, WS)                                              \
            if ((EI) < end) {                                                  \
                int2 p = pe[EI];                                               \
                float w = __int_as_float(p.y);                                 \
                const float4* rp =                                             \
                    (const float4*)(x_in + (size_t)p.x * xstride) + col;       \
                float4 v = *rp;                                                \
                X = fmaf(w, v.x, X); Y = fmaf(w, v.y, Y);                      \
                Z = fmaf(w, v.z, Z); W = fmaf(w, v.w, W);                      \
                WS += w;                                                       \
            }
            for (int e = beg; e < end; e += 16) {
                int e0 = e + slot;
                GBODY(e0,      ax, ay, az, aw, wsa)
                GBODY(e0 + 4,  bx, by, bz, bw, wsb)
                GBODY(e0 + 8,  ax, ay, az, aw, wsa)
                GBODY(e0 + 12, bx, by, bz, bw, wsb)
            }
#undef GBODY
        }
        float sx = ax + bx, sy = ay + by, sz = az + bz, sw = aw + bw;
        float ws = wsa + wsb;
        // reduce across the 4 slots (lane bits 4,5); all lanes get totals
        sx += __shfl_xor(sx, 16); sy += __shfl_xor(sy, 16);
        sz += __shfl_xor(sz, 16); sw += __shfl_xor(sw, 16);
        ws += __shfl_xor(ws, 16);
        sx += __shfl_xor(sx, 32); sy += __shfl_xor(sy, 32);
        sz += __shfl_xor(sz, 32); sw += __shfl_xor(sw, 32);
        ws += __shfl_xor(ws, 32);
        if (lane < 16) {
            float r0 = 0.f, r1 = 0.f, r2 = 0.f, r3 = 0.f;
            if (n < N_NODES) {
                const float4* xr =
                    (const float4*)(x_in + (size_t)n * xstride) + col;
                float4 s = *xr;                       // self term, coalesced
                float shw = 1.0f + ws;
                r0 = fmaf(sc4.x, sx + s.x, sh4.x * shw);
                r1 = fmaf(sc4.y, sy + s.y, sh4.y * shw);
                r2 = fmaf(sc4.z, sz + s.z, sh4.z * shw);
                r3 = fmaf(sc4.w, sw + s.w, sh4.w * shw);
            }
            int lb = nl * LDS_PITCH + col * 4;
            lds[lb] = r0; lds[lb + 1] = r1; lds[lb + 2] = r2; lds[lb + 3] = r3;
        }
    }
    __syncthreads();

    // ---- Stage 1 GEMM: hidden = relu(xin @ W1^T + b1) ----
    float h[16];
#pragma unroll
    for (int jj = 0; jj < 16; ++jj) h[jj] = b1[wid * 16 + jj];
#pragma unroll 4
    for (int k = 0; k < DIM; ++k) {
        float xv = lds[lane * LDS_PITCH + k];
        const float* wr = W1T + k * DIM + wid * 16;   // uniform -> s_load
#pragma unroll
        for (int jj = 0; jj < 16; ++jj) h[jj] = fmaf(xv, wr[jj], h[jj]);
    }
#pragma unroll
    for (int jj = 0; jj < 16; ++jj) h[jj] = fmaxf(h[jj], 0.0f);
    __syncthreads();          // all lds (xin) reads done
#pragma unroll
    for (int jj = 0; jj < 16; ++jj) lds[lane * LDS_PITCH + wid * 16 + jj] = h[jj];
    __syncthreads();

    // ---- Stage 2 GEMM: o = relu(hidden @ W2^T + b2) ----
    float o[16];
#pragma unroll
    for (int jj = 0; jj < 16; ++jj) o[jj] = b2[wid * 16 + jj];
#pragma unroll 4
    for (int k = 0; k < DIM; ++k) {
        float hv = lds[lane * LDS_PITCH + k];
        const float* wr = W2T + k * DIM + wid * 16;
#pragma unroll
        for (int jj = 0; jj < 16; ++jj) o[jj] = fmaf(hv, wr[jj], o[jj]);
    }
    int n = nbase + lane;
    bool valid = (n < N_NODES);
#pragma unroll
    for (int jj = 0; jj < 16; ++jj) o[jj] = fmaxf(o[jj], 0.0f);
    if (valid) {
        float* orow = out + (size_t)n * OUTD + wid * 16;
#pragma unroll
        for (int jj = 0; jj < 16; jj += 4) {
            *(float4*)(orow + jj) = make_float4(o[jj], o[jj + 1], o[jj + 2], o[jj + 3]);
        }
    }

    // ---- BN stat partials: butterfly over 64 lanes; wave wid owns dims
    // [wid*16, wid*16+16). Non-atomic coalesced per-block store.
    float my_s = 0.0f, my_q = 0.0f;
#pragma unroll
    for (int jj = 0; jj < 16; ++jj) {
        float v = valid ? o[jj] : 0.0f;
        float vs = v, vq = v * v;
#pragma unroll
        for (int m = 1; m < 64; m <<= 1) {
            vs += __shfl_xor(vs, m);
            vq += __shfl_xor(vq, m);
        }
        if (lane == jj) { my_s = vs; my_q = vq; }
    }
    if (lane < 16) {
        size_t base = (size_t)blockIdx.x * 128 + wid * 16 + lane;
        pstat[base] = my_s;
        pstat[base + 64] = my_q;
    }
}

// ---------------------------------------------------------------------------
// Reduce per-block BN partials -> scale/shift (bn_prep folded).
__global__ void __launch_bounds__(256) reduce_stats(
    const float* __restrict__ pstat,
    const float* __restrict__ gamma, const float* __restrict__ beta,
    float* __restrict__ ss /* [128]: scale|shift */) {
    __shared__ double part[16][16];
    int b = blockIdx.x;            // 0..7
    int t = threadIdx.x;
    int slot = t & 15;             // 0..7 -> sum(d), 8..15 -> sumsq(d)
    int g = t >> 4;                // group 0..15
    int d = b * 8 + (slot & 7);
    int off = (slot < 8) ? 0 : 64;
    double s = 0.0;
    for (int blk = g; blk < NLBLK; blk += 16)
        s += (double)pstat[(size_t)blk * 128 + off + d];
    part[g][slot] = s;
    __syncthreads();
    if (t < 16) {
        double x = 0.0;
#pragma unroll
        for (int k = 0; k < 16; ++k) x += part[k][t];
        part[0][t] = x;            // column t only -> no hazard
    }
    __syncthreads();
    if (t < 8) {
        int dd = b * 8 + t;
        double mu = part[0][t] / (double)N_NODES;
        double var = part[0][8 + t] / (double)N_NODES - mu * mu;
        float inv = (float)(1.0 / sqrt(var + (double)BN_EPS));
        float sc = gamma[dd] * inv;
        ss[dd] = sc;
        ss[64 + dd] = beta[dd] - (float)mu * sc;
    }
}

// ---------------------------------------------------------------------------
// Final pass: apply BN affine to xs IN PLACE (all 3 layers at once) and
// add-pool per graph. Grid (512 graphs, 4 parts), block 192.
__global__ void bn_pool(float* __restrict__ xs,
                        const int* __restrict__ batch,
                        const float* __restrict__ ss /* [3][128] */,
                        float* __restrict__ pooled) {
    int g = blockIdx.x;
    int part = blockIdx.y;   // 0..3
    int d = threadIdx.x;     // 0..191
    int l = d >> 6, dd = d & 63;
    float sc = ss[l * 128 + dd];
    float sh = ss[l * 128 + 64 + dd];
    int start, end;
    {
        int lo = 0, hi = N_NODES;
        while (lo < hi) { int m = (lo + hi) >> 1; if (batch[m] < g) lo = m + 1; else hi = m; }
        start = lo;
    }
    {
        int lo = start, hi = N_NODES;
        while (lo < hi) { int m = (lo + hi) >> 1; if (batch[m] <= g) lo = m + 1; else hi = m; }
        end = lo;
    }
    float acc = 0.0f;
    for (int n = start + part; n < end; n += 4) {
        float* p = xs + (size_t)n * OUTD + d;
        float v = fmaf(*p, sc, sh);
        *p = v;
        acc += v;
    }
    atomicAdd(&pooled[(size_t)g * OUTD + d], acc);
}

// ---------------------------------------------------------------------------
extern "C" void kernel_launch(void* const* d_in, const int* in_sizes, int n_in,
                              void* d_out, int out_size, void* d_ws, size_t ws_size,
                              hipStream_t stream) {
    const float* x0    = (const float*)d_in[0];
    const int*   ei    = (const int*)d_in[1];
    const float* ew    = (const float*)d_in[2];
    const int*   batch = (const int*)d_in[3];
    const float* W1    = (const float*)d_in[5];
    const float* b1    = (const float*)d_in[6];
    const float* W2    = (const float*)d_in[7];
    const float* b2    = (const float*)d_in[8];
    const float* gamma = (const float*)d_in[9];
    const float* beta  = (const float*)d_in[10];

    float* pooled = (float*)d_out;                      // [512, 192]
    float* xs     = pooled + (size_t)N_GRAPHS * OUTD;   // [100000, 192]

    const int* src = ei;
    const int* dst = ei + N_EDGES;

    // Workspace layout (~21.5 MB):
    // pe[E] | pp[E] | seg[N+4] | hist[NPBLK*NBUK] | base[NPBLK*NBUK]
    // | tot[NBUK+4] | bstart[NBUK+4] | W1T | W2T | idaff | ss | pstat
    int2*  pe     = (int2*)d_ws;
    int2*  pp     = pe + N_EDGES;
    int*   seg    = (int*)(pp + N_EDGES);
    int*   hist   = seg + N_NODES + 4;
    int*   pbase  = hist + (size_t)NPBLK * NBUK;
    int*   tot    = pbase + (size_t)NPBLK * NBUK;
    int*   bstart = tot + NBUK + 4;
    float* W1T    = (float*)(bstart + NBUK + 4);
    float* W2T    = W1T + N_LAYERS * DIM * DIM;
    float* idaff  = W2T + N_LAYERS * DIM * DIM;    // 128 floats
    float* ss     = idaff + 128;                   // 3*128 floats
    float* pstat  = ss + N_LAYERS * 128;           // NLBLK*128 floats

    transpose_w<<<(N_LAYERS * DIM * DIM + 255) / 256, 256, 0, stream>>>(
        W1, W2, W1T, W2T, idaff);

    // Two-level binning: contention-free partition -> per-bucket CSR.
    hipMemsetAsync(tot, 0, (NBUK + 4) * sizeof(int), stream);
    part_hist<<<NPBLK, 256, 0, stream>>>(dst, hist, tot);
    scan196<<<1, 256, 0, stream>>>(tot, bstart);
    base_fill<<<NBUK, 256, 0, stream>>>(hist, bstart, pbase);
    part_scatter<<<NPBLK, 256, 0, stream>>>(src, dst, ew, pbase, pp);
    csr_build<<<NBUK, 256, 0, stream>>>(pp, bstart, seg, pe);

    for (int i = 0; i < N_LAYERS; ++i) {
        const float* xin = (i == 0) ? x0 : (xs + (size_t)(i - 1) * DIM);
        int xstride = (i == 0) ? DIM : OUTD;
        const float* affine = (i == 0) ? idaff : (ss + (size_t)(i - 1) * 128);

        layer_kernel<<<NLBLK, 256, 0, stream>>>(
            xin, xstride, seg, pe, affine,
            W1T + (size_t)i * DIM * DIM, b1 + (size_t)i * DIM,
            W2T + (size_t)i * DIM * DIM, b2 + (size_t)i * DIM,
            xs + (size_t)i * DIM, pstat);

        reduce_stats<<<8, 256, 0, stream>>>(
            pstat, gamma + (size_t)i * DIM, beta + (size_t)i * DIM,
            ss + (size_t)i * 128);
    }

    hipMemsetAsync(pooled, 0, (size_t)N_GRAPHS * OUTD * sizeof(float), stream);
    dim3 pgrid(N_GRAPHS, 4);
    bn_pool<<<pgrid, OUTD, 0, stream>>>(xs, batch, ss, pooled);
}